// Round 1
// baseline (6462.807 us; speedup 1.0000x reference)
//
#include <hip/hip_runtime.h>
#include <cmath>

#define BN 4
#define HF 256
#define WF 448
#define HWF (HF*WF)   // 114688

__device__ __forceinline__ float clampf(float v, float lo, float hi) {
    return fminf(fmaxf(v, lo), hi);
}

// ---- gate conv: relu(conv3x3_pad1(x[0,:6], wr, br)) spatial mean, batch 0 only ----
__global__ void gate_conv_kernel(const float* __restrict__ x,
                                 const float* __restrict__ wr,
                                 const float* __restrict__ br,
                                 float* __restrict__ rmean) {
    int co = blockIdx.x;            // 0..31
    __shared__ float wsh[54];
    if (threadIdx.x < 54) wsh[threadIdx.x] = wr[co*54 + threadIdx.x];
    __syncthreads();
    float bias = br[co];
    double acc = 0.0;
    for (int p = threadIdx.x; p < HWF; p += blockDim.x) {
        int y = p / WF, xx = p % WF;
        float s = bias;
        for (int ci = 0; ci < 6; ++ci) {
            const float* ip = x + (size_t)ci*HWF;      // batch 0
            const float* wp = wsh + ci*9;
            #pragma unroll
            for (int ky = 0; ky < 3; ++ky) {
                int iy = y + ky - 1;
                if ((unsigned)iy >= HF) continue;
                #pragma unroll
                for (int kx = 0; kx < 3; ++kx) {
                    int ix = xx + kx - 1;
                    if ((unsigned)ix >= WF) continue;
                    s += ip[iy*WF + ix] * wp[ky*3+kx];
                }
            }
        }
        acc += (double)fmaxf(s, 0.0f);
    }
    __shared__ double red[256];
    red[threadIdx.x] = acc;
    __syncthreads();
    for (int off = 128; off > 0; off >>= 1) {
        if ((int)threadIdx.x < off) red[threadIdx.x] += red[threadIdx.x + off];
        __syncthreads();
    }
    if (threadIdx.x == 0) rmean[co] = (float)(red[0] / (double)HWF);
}

// ---- gate FC: v = sigmoid(r@wl.T + bl); v = v/(sum+1e-6)*4.5; g = round(clip(v,0,1)) ----
__global__ void gate_fc_kernel(const float* __restrict__ rmean,
                               const float* __restrict__ wl,
                               const float* __restrict__ bl,
                               float* __restrict__ g) {
    __shared__ double v[9];
    int i = threadIdx.x;
    if (i < 9) {
        double t = (double)bl[i];
        for (int c = 0; c < 32; ++c) t += (double)rmean[c] * (double)wl[i*32+c];
        v[i] = 1.0 / (1.0 + exp(-t));
    }
    __syncthreads();
    if (i == 0) {
        double s = 0.0;
        for (int k = 0; k < 9; ++k) s += v[k];
        for (int k = 0; k < 9; ++k) {
            double vn = v[k] / (s + 1e-6) * 4.5;
            vn = vn < 0.0 ? 0.0 : (vn > 1.0 ? 1.0 : vn);
            g[k] = (float)rint(vn);
        }
    }
}

// ---- init: flow=0, mask=0, w0=img0, w1=img1 ----
__global__ void init_kernel(const float* __restrict__ x,
                            float* __restrict__ flow, float* __restrict__ mask,
                            float* __restrict__ w0, float* __restrict__ w1) {
    int idx = blockIdx.x * blockDim.x + threadIdx.x;
    if (idx < BN*4*HWF) flow[idx] = 0.0f;
    if (idx < BN*HWF)   mask[idx] = 0.0f;
    if (idx < BN*3*HWF) {
        int b = idx / (3*HWF), r = idx % (3*HWF);
        w0[idx] = x[(size_t)b*6*HWF + r];
        w1[idx] = x[(size_t)b*6*HWF + 3*HWF + r];
    }
}

// ---- prepare t = concat(resize([img0,img1,w0,w1,mask]), resize(flow)/s), (B,17,sh,sw) ----
__global__ void prepare_kernel(const float* __restrict__ x,
                               const float* __restrict__ w0buf, const float* __restrict__ w1buf,
                               const float* __restrict__ mask, const float* __restrict__ flow,
                               const float* __restrict__ g, int gi,
                               float* __restrict__ t, int s, int sh, int sw) {
    if (g[gi] == 0.0f) return;
    int idx = blockIdx.x * blockDim.x + threadIdx.x;
    int total = BN*17*sh*sw;
    if (idx >= total) return;
    int ox = idx % sw;
    int oy = (idx / sw) % sh;
    int c  = (idx / (sw*sh)) % 17;
    int b  = idx / (sw*sh*17);
    const float* src; float mult = 1.0f;
    if (c < 6)        src = x + ((size_t)b*6 + c)*HWF;
    else if (c < 9)   src = w0buf + ((size_t)b*3 + (c-6))*HWF;
    else if (c < 12)  src = w1buf + ((size_t)b*3 + (c-9))*HWF;
    else if (c == 12) src = mask + (size_t)b*HWF;
    else { src = flow + ((size_t)b*4 + (c-13))*HWF; mult = 1.0f / (float)s; }
    float val;
    if (s == 1) {
        val = src[oy*WF + ox];
    } else {
        int nt = 2*s;
        float posy = (oy + 0.5f)*(float)s - 0.5f;
        float posx = (ox + 0.5f)*(float)s - 0.5f;
        int jy0 = s*oy - s/2;
        int jx0 = s*ox - s/2;
        float wy[8], wx[8], sy = 0.f, sx = 0.f;
        for (int k = 0; k < nt; ++k) {
            int j = jy0 + k;
            float ww = 1.0f - fabsf((float)j - posy)/(float)s;
            if (j < 0 || j >= HF) ww = 0.f;
            wy[k] = ww; sy += ww;
        }
        for (int k = 0; k < nt; ++k) {
            int j = jx0 + k;
            float ww = 1.0f - fabsf((float)j - posx)/(float)s;
            if (j < 0 || j >= WF) ww = 0.f;
            wx[k] = ww; sx += ww;
        }
        float acc = 0.f;
        for (int a = 0; a < nt; ++a) {
            if (wy[a] == 0.f) continue;
            const float* rp = src + (jy0 + a)*WF;
            float rowacc = 0.f;
            for (int bb = 0; bb < nt; ++bb) {
                if (wx[bb] == 0.f) continue;
                rowacc += wx[bb] * rp[jx0 + bb];
            }
            acc += wy[a] * rowacc;
        }
        val = acc / (sy * sx);
    }
    t[idx] = val * mult;
}

// ---- generic 3x3 conv (stride 1 pad 1, or stride 2 pad (0,1)), optional relu + residual ----
__global__ void conv3x3_kernel(const float* __restrict__ in,
                               const float* __restrict__ w,
                               const float* __restrict__ bias,
                               const float* __restrict__ resid,
                               const float* __restrict__ g, int gi,
                               float* __restrict__ out,
                               int Cin, int Cout, int Hin, int Win,
                               int Hout, int Wout, int stride, int pad,
                               int do_relu) {
    if (g[gi] == 0.0f) return;
    int idx = blockIdx.x * blockDim.x + threadIdx.x;
    int total = BN*Cout*Hout*Wout;
    if (idx >= total) return;
    int xx = idx % Wout;
    int y  = (idx / Wout) % Hout;
    int co = (idx / (Wout*Hout)) % Cout;
    int b  = idx / (Wout*Hout*Cout);
    float acc = bias[co];
    const float* ib = in + (size_t)b*Cin*Hin*Win;
    const float* wb = w + (size_t)co*Cin*9;
    for (int ci = 0; ci < Cin; ++ci) {
        const float* ip = ib + (size_t)ci*Hin*Win;
        const float* wp = wb + ci*9;
        #pragma unroll
        for (int ky = 0; ky < 3; ++ky) {
            int iy = y*stride + ky - pad;
            if ((unsigned)iy >= (unsigned)Hin) continue;
            const float* rp = ip + iy*Win;
            #pragma unroll
            for (int kx = 0; kx < 3; ++kx) {
                int ix = xx*stride + kx - pad;
                if ((unsigned)ix >= (unsigned)Win) continue;
                acc += rp[ix] * wp[ky*3+kx];
            }
        }
    }
    if (do_relu) acc = fmaxf(acc, 0.0f);
    if (resid) acc += resid[idx];
    out[idx] = acc;
}

// ---- transposed conv 4x4 stride 2 'SAME' (pad 2,2 on dilated input), kernel unflipped ----
__global__ void deconv_kernel(const float* __restrict__ t,
                              const float* __restrict__ wl,
                              const float* __restrict__ bl,
                              const float* __restrict__ g, int gi,
                              float* __restrict__ out,
                              int h2, int w2) {
    if (g[gi] == 0.0f) return;
    int ho = 2*h2, wo = 2*w2;
    int idx = blockIdx.x * blockDim.x + threadIdx.x;
    int total = BN*5*ho*wo;
    if (idx >= total) return;
    int xx = idx % wo;
    int y  = (idx / wo) % ho;
    int o  = (idx / (wo*ho)) % 5;
    int b  = idx / (wo*ho*5);
    float acc = bl[o];
    int p = y & 1, q = xx & 1;
    const float* tb = t + (size_t)b*80*h2*w2;
    for (int dy = 0; dy < 2; ++dy) {
        int ky = p + 2*dy;
        int iy = (y + ky - 2) >> 1;
        if ((unsigned)iy >= (unsigned)h2) continue;
        for (int dx = 0; dx < 2; ++dx) {
            int kx = q + 2*dx;
            int ix = (xx + kx - 2) >> 1;
            if ((unsigned)ix >= (unsigned)w2) continue;
            const float* tp = tb + iy*w2 + ix;
            const float* wp = wl + (size_t)o*80*16 + ky*4 + kx;
            for (int i = 0; i < 80; ++i)
                acc += tp[(size_t)i*h2*w2] * wp[i*16];
        }
    }
    out[idx] = acc;
}

// ---- bilinear upsample (factor f) + gated accumulate into flow (c<4, *2s) / mask (c==4) ----
__global__ void upsample_accum_kernel(const float* __restrict__ tmp,
                                      const float* __restrict__ g, int gi,
                                      float* __restrict__ flow, float* __restrict__ mask,
                                      int h, int w, int f, float fdscale) {
    float gg = g[gi];
    if (gg == 0.0f) return;
    int idx = blockIdx.x * blockDim.x + threadIdx.x;
    int total = BN*5*HWF;
    if (idx >= total) return;
    int xx = idx % WF;
    int y  = (idx / WF) % HF;
    int c  = (idx / HWF) % 5;
    int b  = idx / (HWF*5);
    float posy = (y + 0.5f)/(float)f - 0.5f;
    float posx = (xx + 0.5f)/(float)f - 0.5f;
    float y0f = floorf(posy), x0f = floorf(posx);
    int jy0 = (int)y0f, jx0 = (int)x0f;
    float fy = posy - y0f, fx = posx - x0f;
    int jy1 = min(jy0 + 1, h-1), jx1 = min(jx0 + 1, w-1);
    jy0 = max(jy0, 0); jx0 = max(jx0, 0);
    const float* tp = tmp + ((size_t)(b*5 + c))*h*w;
    float v00 = tp[jy0*w + jx0], v01 = tp[jy0*w + jx1];
    float v10 = tp[jy1*w + jx0], v11 = tp[jy1*w + jx1];
    float val = v00*(1-fx)*(1-fy) + v01*fx*(1-fy) + v10*(1-fx)*fy + v11*fx*fy;
    int p2 = y*WF + xx;
    if (c < 4) flow[((size_t)b*4 + c)*HWF + p2] += val * fdscale * gg;
    else       mask[(size_t)b*HWF + p2] += val * gg;
}

// ---- backward warp of img0/img1 by flow channels (0,1)/(2,3) ----
__global__ void warp_kernel(const float* __restrict__ x,
                            const float* __restrict__ flow,
                            const float* __restrict__ g, int gi,
                            float* __restrict__ w0, float* __restrict__ w1) {
    if (g[gi] == 0.0f) return;
    int idx = blockIdx.x*blockDim.x + threadIdx.x;
    int total = BN*6*HWF;
    if (idx >= total) return;
    int p  = idx % HWF;
    int c  = (idx / HWF) % 6;
    int b  = idx / (HWF*6);
    int xx = p % WF, y = p / WF;
    int which = (c >= 3) ? 1 : 0;
    const float* fl = flow + ((size_t)b*4 + which*2)*HWF;
    float sx = clampf((float)xx + fl[p], 0.f, (float)(WF-1));
    float sy = clampf((float)y  + fl[HWF + p], 0.f, (float)(HF-1));
    float x0f = floorf(sx), y0f = floorf(sy);
    int x0 = (int)x0f, y0 = (int)y0f;
    int x1 = min(x0 + 1, WF - 1), y1 = min(y0 + 1, HF - 1);
    float wx = sx - x0f, wy = sy - y0f;
    const float* im = x + ((size_t)b*6 + c)*HWF;
    float v00 = im[y0*WF + x0], v01 = im[y0*WF + x1];
    float v10 = im[y1*WF + x0], v11 = im[y1*WF + x1];
    float val = v00*(1-wx)*(1-wy) + v01*wx*(1-wy) + v10*(1-wx)*wy + v11*wx*wy;
    float* dst = which ? w1 : w0;
    dst[((size_t)b*3 + (c - which*3))*HWF + p] = val;
}

// ---- final: out = clip(w0*sigmoid(mask) + w1*(1-sigmoid(mask)), 0, 1) ----
__global__ void final_kernel(const float* __restrict__ w0, const float* __restrict__ w1,
                             const float* __restrict__ mask, float* __restrict__ outp) {
    int idx = blockIdx.x*blockDim.x + threadIdx.x;
    if (idx >= BN*3*HWF) return;
    int p = idx % HWF;
    int b = idx / (3*HWF);
    float m = 1.0f / (1.0f + expf(-mask[(size_t)b*HWF + p]));
    float val = w0[idx]*m + w1[idx]*(1.0f - m);
    outp[idx] = clampf(val, 0.0f, 1.0f);
}

extern "C" void kernel_launch(void* const* d_in, const int* in_sizes, int n_in,
                              void* d_out, int out_size, void* d_ws, size_t ws_size,
                              hipStream_t stream) {
    const float* x     = (const float*)d_in[0];
    const float* wr    = (const float*)d_in[1];
    const float* br    = (const float*)d_in[2];
    const float* wl    = (const float*)d_in[3];
    const float* bl    = (const float*)d_in[4];
    const float* w0a   = (const float*)d_in[5];
    const float* b0a   = (const float*)d_in[6];
    const float* w0b   = (const float*)d_in[7];
    const float* b0b   = (const float*)d_in[8];
    const float* wcb   = (const float*)d_in[9];
    const float* bcb   = (const float*)d_in[10];
    const float* wlast = (const float*)d_in[11];
    const float* blast = (const float*)d_in[12];

    float* ws    = (float*)d_ws;
    float* g     = ws;          // 16
    float* rmean = ws + 16;     // 32
    size_t off = 48;
    float* flow = ws + off; off += (size_t)BN*4*HWF;
    float* mask = ws + off; off += (size_t)BN*1*HWF;
    float* wb0  = ws + off; off += (size_t)BN*3*HWF;
    float* wb1  = ws + off; off += (size_t)BN*3*HWF;
    float* tin  = ws + off; off += (size_t)BN*17*HWF;
    float* t0   = ws + off; off += (size_t)BN*40*(HF/2)*(WF/2);
    float* t1   = ws + off; off += (size_t)BN*80*(HF/4)*(WF/4);
    float* ra   = ws + off; off += (size_t)BN*80*(HF/4)*(WF/4);
    float* rb   = ws + off; off += (size_t)BN*80*(HF/4)*(WF/4);
    float* tmpb = ws + off; off += (size_t)BN*5*(HF/2)*(WF/2);

    gate_conv_kernel<<<32, 256, 0, stream>>>(x, wr, br, rmean);
    gate_fc_kernel<<<1, 64, 0, stream>>>(rmean, wl, bl, g);
    {
        int n = BN*4*HWF;
        init_kernel<<<(n+255)/256, 256, 0, stream>>>(x, flow, mask, wb0, wb1);
    }
    const int SC[9] = {4,4,4,2,2,2,1,1,1};
    for (int i = 0; i < 9; ++i) {
        int s = SC[i];
        int sh = HF/s, sw = WF/s;
        int h = sh/2, w = sw/2;
        int h2 = h/2, w2 = w/2;
        {
            int n = BN*17*sh*sw;
            prepare_kernel<<<(n+255)/256,256,0,stream>>>(x, wb0, wb1, mask, flow, g, i, tin, s, sh, sw);
        }
        {
            int n = BN*40*h*w;
            conv3x3_kernel<<<(n+255)/256,256,0,stream>>>(tin, w0a + (size_t)i*40*17*9, b0a + i*40,
                nullptr, g, i, t0, 17, 40, sh, sw, h, w, 2, 0, 1);
        }
        {
            int n = BN*80*h2*w2;
            conv3x3_kernel<<<(n+255)/256,256,0,stream>>>(t0, w0b + (size_t)i*80*40*9, b0b + i*80,
                nullptr, g, i, t1, 40, 80, h, w, h2, w2, 2, 0, 1);
        }
        const float* cin = t1;
        float* cout = ra;
        for (int j = 0; j < 4; ++j) {
            int n = BN*80*h2*w2;
            const float* res = (j == 3) ? t1 : nullptr;
            conv3x3_kernel<<<(n+255)/256,256,0,stream>>>(cin,
                wcb + ((size_t)i*4 + j)*80*80*9, bcb + ((size_t)i*4 + j)*80,
                res, g, i, cout, 80, 80, h2, w2, h2, w2, 1, 1, 1);
            cin = cout;
            cout = (cout == ra) ? rb : ra;
        }
        {
            int n = BN*5*h*w;
            deconv_kernel<<<(n+255)/256,256,0,stream>>>(cin, wlast + (size_t)i*5*80*16, blast + i*5,
                g, i, tmpb, h2, w2);
        }
        {
            int n = BN*5*HWF;
            upsample_accum_kernel<<<(n+255)/256,256,0,stream>>>(tmpb, g, i, flow, mask, h, w, 2*s, (float)(2*s));
        }
        {
            int n = BN*6*HWF;
            warp_kernel<<<(n+255)/256,256,0,stream>>>(x, flow, g, i, wb0, wb1);
        }
    }
    {
        int n = BN*3*HWF;
        final_kernel<<<(n+255)/256,256,0,stream>>>(wb0, wb1, mask, (float*)d_out);
    }
}

// Round 2
// 3839.310 us; speedup vs baseline: 1.6833x; 1.6833x over previous
//
#include <hip/hip_runtime.h>
#include <cmath>

#define BN 4
#define HF 256
#define WF 448
#define HWF (HF*WF)   // 114688
#define GCHUNKS 64
#define GPIX (HWF/GCHUNKS)   // 1792

__device__ __forceinline__ float clampf(float v, float lo, float hi) {
    return fminf(fmaxf(v, lo), hi);
}

// ---- gate conv partials: relu(conv3x3_pad1(x[0,:6], wr, br)), partial spatial sums ----
// grid = 32*GCHUNKS blocks; block (co,chunk) reduces GPIX pixels -> partial[co*GCHUNKS+chunk]
__global__ void gate_conv_kernel(const float* __restrict__ x,
                                 const float* __restrict__ wr,
                                 const float* __restrict__ br,
                                 double* __restrict__ partial) {
    int co    = blockIdx.x >> 6;
    int chunk = blockIdx.x & 63;
    __shared__ float wsh[54];
    if (threadIdx.x < 54) wsh[threadIdx.x] = wr[co*54 + threadIdx.x];
    __syncthreads();
    float bias = br[co];
    float facc = 0.0f;
    int p0 = chunk * GPIX;
    for (int k = threadIdx.x; k < GPIX; k += blockDim.x) {
        int p = p0 + k;
        int y = p / WF, xx = p % WF;
        float s = bias;
        #pragma unroll
        for (int ci = 0; ci < 6; ++ci) {
            const float* ip = x + (size_t)ci*HWF;      // batch 0
            const float* wp = wsh + ci*9;
            #pragma unroll
            for (int ky = 0; ky < 3; ++ky) {
                int iy = y + ky - 1;
                if ((unsigned)iy >= HF) continue;
                #pragma unroll
                for (int kx = 0; kx < 3; ++kx) {
                    int ix = xx + kx - 1;
                    if ((unsigned)ix >= WF) continue;
                    s += ip[iy*WF + ix] * wp[ky*3+kx];
                }
            }
        }
        facc += fmaxf(s, 0.0f);
    }
    __shared__ double red[256];
    red[threadIdx.x] = (double)facc;
    __syncthreads();
    for (int off = 128; off > 0; off >>= 1) {
        if ((int)threadIdx.x < off) red[threadIdx.x] += red[threadIdx.x + off];
        __syncthreads();
    }
    if (threadIdx.x == 0) partial[co*GCHUNKS + chunk] = red[0];
}

// ---- gate FC: reduce partials -> rmean; v = sigmoid(r@wl.T+bl); normalize; round ----
__global__ void gate_fc_kernel(const double* __restrict__ partial,
                               const float* __restrict__ wl,
                               const float* __restrict__ bl,
                               float* __restrict__ g) {
    __shared__ double rm[32];
    __shared__ double v[9];
    int i = threadIdx.x;
    if (i < 32) {
        double s = 0.0;
        for (int k = 0; k < GCHUNKS; ++k) s += partial[i*GCHUNKS + k];
        rm[i] = s / (double)HWF;
    }
    __syncthreads();
    if (i < 9) {
        double t = (double)bl[i];
        for (int c = 0; c < 32; ++c) t += rm[c] * (double)wl[i*32+c];
        v[i] = 1.0 / (1.0 + exp(-t));
    }
    __syncthreads();
    if (i == 0) {
        double s = 0.0;
        for (int k = 0; k < 9; ++k) s += v[k];
        for (int k = 0; k < 9; ++k) {
            double vn = v[k] / (s + 1e-6) * 4.5;
            vn = vn < 0.0 ? 0.0 : (vn > 1.0 ? 1.0 : vn);
            g[k] = (float)rint(vn);
        }
    }
}

// ---- init: flow=0, mask=0, w0=img0, w1=img1 ----
__global__ void init_kernel(const float* __restrict__ x,
                            float* __restrict__ flow, float* __restrict__ mask,
                            float* __restrict__ w0, float* __restrict__ w1) {
    int idx = blockIdx.x * blockDim.x + threadIdx.x;
    if (idx < BN*4*HWF) flow[idx] = 0.0f;
    if (idx < BN*HWF)   mask[idx] = 0.0f;
    if (idx < BN*3*HWF) {
        int b = idx / (3*HWF), r = idx % (3*HWF);
        w0[idx] = x[(size_t)b*6*HWF + r];
        w1[idx] = x[(size_t)b*6*HWF + 3*HWF + r];
    }
}

// ---- prepare t = concat(resize([img0,img1,w0,w1,mask]), resize(flow)/s), (B,17,sh,sw) ----
__global__ void prepare_kernel(const float* __restrict__ x,
                               const float* __restrict__ w0buf, const float* __restrict__ w1buf,
                               const float* __restrict__ mask, const float* __restrict__ flow,
                               const float* __restrict__ g, int gi,
                               float* __restrict__ t, int s, int sh, int sw) {
    if (g[gi] == 0.0f) return;
    int idx = blockIdx.x * blockDim.x + threadIdx.x;
    int total = BN*17*sh*sw;
    if (idx >= total) return;
    int ox = idx % sw;
    int oy = (idx / sw) % sh;
    int c  = (idx / (sw*sh)) % 17;
    int b  = idx / (sw*sh*17);
    const float* src; float mult = 1.0f;
    if (c < 6)        src = x + ((size_t)b*6 + c)*HWF;
    else if (c < 9)   src = w0buf + ((size_t)b*3 + (c-6))*HWF;
    else if (c < 12)  src = w1buf + ((size_t)b*3 + (c-9))*HWF;
    else if (c == 12) src = mask + (size_t)b*HWF;
    else { src = flow + ((size_t)b*4 + (c-13))*HWF; mult = 1.0f / (float)s; }
    float val;
    if (s == 1) {
        val = src[oy*WF + ox];
    } else {
        int nt = 2*s;
        float posy = (oy + 0.5f)*(float)s - 0.5f;
        float posx = (ox + 0.5f)*(float)s - 0.5f;
        int jy0 = s*oy - s/2;
        int jx0 = s*ox - s/2;
        float wy[8], wx[8], sy = 0.f, sx = 0.f;
        for (int k = 0; k < nt; ++k) {
            int j = jy0 + k;
            float ww = 1.0f - fabsf((float)j - posy)/(float)s;
            if (j < 0 || j >= HF) ww = 0.f;
            wy[k] = ww; sy += ww;
        }
        for (int k = 0; k < nt; ++k) {
            int j = jx0 + k;
            float ww = 1.0f - fabsf((float)j - posx)/(float)s;
            if (j < 0 || j >= WF) ww = 0.f;
            wx[k] = ww; sx += ww;
        }
        float acc = 0.f;
        for (int a = 0; a < nt; ++a) {
            if (wy[a] == 0.f) continue;
            const float* rp = src + (jy0 + a)*WF;
            float rowacc = 0.f;
            for (int bb = 0; bb < nt; ++bb) {
                if (wx[bb] == 0.f) continue;
                rowacc += wx[bb] * rp[jx0 + bb];
            }
            acc += wy[a] * rowacc;
        }
        val = acc / (sy * sx);
    }
    t[idx] = val * mult;
}

// ---- generic 3x3 conv (stride 1 pad 1, or stride 2 pad (0,1)), optional relu + residual ----
__global__ void conv3x3_kernel(const float* __restrict__ in,
                               const float* __restrict__ w,
                               const float* __restrict__ bias,
                               const float* __restrict__ resid,
                               const float* __restrict__ g, int gi,
                               float* __restrict__ out,
                               int Cin, int Cout, int Hin, int Win,
                               int Hout, int Wout, int stride, int pad,
                               int do_relu) {
    if (g[gi] == 0.0f) return;
    int idx = blockIdx.x * blockDim.x + threadIdx.x;
    int total = BN*Cout*Hout*Wout;
    if (idx >= total) return;
    int xx = idx % Wout;
    int y  = (idx / Wout) % Hout;
    int co = (idx / (Wout*Hout)) % Cout;
    int b  = idx / (Wout*Hout*Cout);
    float acc = bias[co];
    const float* ib = in + (size_t)b*Cin*Hin*Win;
    const float* wb = w + (size_t)co*Cin*9;
    for (int ci = 0; ci < Cin; ++ci) {
        const float* ip = ib + (size_t)ci*Hin*Win;
        const float* wp = wb + ci*9;
        #pragma unroll
        for (int ky = 0; ky < 3; ++ky) {
            int iy = y*stride + ky - pad;
            if ((unsigned)iy >= (unsigned)Hin) continue;
            const float* rp = ip + iy*Win;
            #pragma unroll
            for (int kx = 0; kx < 3; ++kx) {
                int ix = xx*stride + kx - pad;
                if ((unsigned)ix >= (unsigned)Win) continue;
                acc += rp[ix] * wp[ky*3+kx];
            }
        }
    }
    if (do_relu) acc = fmaxf(acc, 0.0f);
    if (resid) acc += resid[idx];
    out[idx] = acc;
}

// ---- transposed conv 4x4 stride 2 'SAME' (pad 2,2 on dilated input), kernel unflipped ----
__global__ void deconv_kernel(const float* __restrict__ t,
                              const float* __restrict__ wl,
                              const float* __restrict__ bl,
                              const float* __restrict__ g, int gi,
                              float* __restrict__ out,
                              int h2, int w2) {
    if (g[gi] == 0.0f) return;
    int ho = 2*h2, wo = 2*w2;
    int idx = blockIdx.x * blockDim.x + threadIdx.x;
    int total = BN*5*ho*wo;
    if (idx >= total) return;
    int xx = idx % wo;
    int y  = (idx / wo) % ho;
    int o  = (idx / (wo*ho)) % 5;
    int b  = idx / (wo*ho*5);
    float acc = bl[o];
    int p = y & 1, q = xx & 1;
    const float* tb = t + (size_t)b*80*h2*w2;
    for (int dy = 0; dy < 2; ++dy) {
        int ky = p + 2*dy;
        int iy = (y + ky - 2) >> 1;
        if ((unsigned)iy >= (unsigned)h2) continue;
        for (int dx = 0; dx < 2; ++dx) {
            int kx = q + 2*dx;
            int ix = (xx + kx - 2) >> 1;
            if ((unsigned)ix >= (unsigned)w2) continue;
            const float* tp = tb + iy*w2 + ix;
            const float* wp = wl + (size_t)o*80*16 + ky*4 + kx;
            for (int i = 0; i < 80; ++i)
                acc += tp[(size_t)i*h2*w2] * wp[i*16];
        }
    }
    out[idx] = acc;
}

// ---- bilinear upsample (factor f) + gated accumulate into flow (c<4, *2s) / mask (c==4) ----
__global__ void upsample_accum_kernel(const float* __restrict__ tmp,
                                      const float* __restrict__ g, int gi,
                                      float* __restrict__ flow, float* __restrict__ mask,
                                      int h, int w, int f, float fdscale) {
    float gg = g[gi];
    if (gg == 0.0f) return;
    int idx = blockIdx.x * blockDim.x + threadIdx.x;
    int total = BN*5*HWF;
    if (idx >= total) return;
    int xx = idx % WF;
    int y  = (idx / WF) % HF;
    int c  = (idx / HWF) % 5;
    int b  = idx / (HWF*5);
    float posy = (y + 0.5f)/(float)f - 0.5f;
    float posx = (xx + 0.5f)/(float)f - 0.5f;
    float y0f = floorf(posy), x0f = floorf(posx);
    int jy0 = (int)y0f, jx0 = (int)x0f;
    float fy = posy - y0f, fx = posx - x0f;
    int jy1 = min(jy0 + 1, h-1), jx1 = min(jx0 + 1, w-1);
    jy0 = max(jy0, 0); jx0 = max(jx0, 0);
    const float* tp = tmp + ((size_t)(b*5 + c))*h*w;
    float v00 = tp[jy0*w + jx0], v01 = tp[jy0*w + jx1];
    float v10 = tp[jy1*w + jx0], v11 = tp[jy1*w + jx1];
    float val = v00*(1-fx)*(1-fy) + v01*fx*(1-fy) + v10*(1-fx)*fy + v11*fx*fy;
    int p2 = y*WF + xx;
    if (c < 4) flow[((size_t)b*4 + c)*HWF + p2] += val * fdscale * gg;
    else       mask[(size_t)b*HWF + p2] += val * gg;
}

// ---- backward warp of img0/img1 by flow channels (0,1)/(2,3) ----
__global__ void warp_kernel(const float* __restrict__ x,
                            const float* __restrict__ flow,
                            const float* __restrict__ g, int gi,
                            float* __restrict__ w0, float* __restrict__ w1) {
    if (g[gi] == 0.0f) return;
    int idx = blockIdx.x*blockDim.x + threadIdx.x;
    int total = BN*6*HWF;
    if (idx >= total) return;
    int p  = idx % HWF;
    int c  = (idx / HWF) % 6;
    int b  = idx / (HWF*6);
    int xx = p % WF, y = p / WF;
    int which = (c >= 3) ? 1 : 0;
    const float* fl = flow + ((size_t)b*4 + which*2)*HWF;
    float sx = clampf((float)xx + fl[p], 0.f, (float)(WF-1));
    float sy = clampf((float)y  + fl[HWF + p], 0.f, (float)(HF-1));
    float x0f = floorf(sx), y0f = floorf(sy);
    int x0 = (int)x0f, y0 = (int)y0f;
    int x1 = min(x0 + 1, WF - 1), y1 = min(y0 + 1, HF - 1);
    float wx = sx - x0f, wy = sy - y0f;
    const float* im = x + ((size_t)b*6 + c)*HWF;
    float v00 = im[y0*WF + x0], v01 = im[y0*WF + x1];
    float v10 = im[y1*WF + x0], v11 = im[y1*WF + x1];
    float val = v00*(1-wx)*(1-wy) + v01*wx*(1-wy) + v10*(1-wx)*wy + v11*wx*wy;
    float* dst = which ? w1 : w0;
    dst[((size_t)b*3 + (c - which*3))*HWF + p] = val;
}

// ---- final: out = clip(w0*sigmoid(mask) + w1*(1-sigmoid(mask)), 0, 1) ----
__global__ void final_kernel(const float* __restrict__ w0, const float* __restrict__ w1,
                             const float* __restrict__ mask, float* __restrict__ outp) {
    int idx = blockIdx.x*blockDim.x + threadIdx.x;
    if (idx >= BN*3*HWF) return;
    int p = idx % HWF;
    int b = idx / (3*HWF);
    float m = 1.0f / (1.0f + expf(-mask[(size_t)b*HWF + p]));
    float val = w0[idx]*m + w1[idx]*(1.0f - m);
    outp[idx] = clampf(val, 0.0f, 1.0f);
}

extern "C" void kernel_launch(void* const* d_in, const int* in_sizes, int n_in,
                              void* d_out, int out_size, void* d_ws, size_t ws_size,
                              hipStream_t stream) {
    const float* x     = (const float*)d_in[0];
    const float* wr    = (const float*)d_in[1];
    const float* br    = (const float*)d_in[2];
    const float* wl    = (const float*)d_in[3];
    const float* bl    = (const float*)d_in[4];
    const float* w0a   = (const float*)d_in[5];
    const float* b0a   = (const float*)d_in[6];
    const float* w0b   = (const float*)d_in[7];
    const float* b0b   = (const float*)d_in[8];
    const float* wcb   = (const float*)d_in[9];
    const float* bcb   = (const float*)d_in[10];
    const float* wlast = (const float*)d_in[11];
    const float* blast = (const float*)d_in[12];

    float* ws      = (float*)d_ws;
    double* partial = (double*)d_ws;             // 32*GCHUNKS doubles = 4096 floats
    float* g       = ws + 4096;                  // 16 floats
    size_t off = 4112;
    float* flow = ws + off; off += (size_t)BN*4*HWF;
    float* mask = ws + off; off += (size_t)BN*1*HWF;
    float* wb0  = ws + off; off += (size_t)BN*3*HWF;
    float* wb1  = ws + off; off += (size_t)BN*3*HWF;
    float* tin  = ws + off; off += (size_t)BN*17*HWF;
    float* t0   = ws + off; off += (size_t)BN*40*(HF/2)*(WF/2);
    float* t1   = ws + off; off += (size_t)BN*80*(HF/4)*(WF/4);
    float* ra   = ws + off; off += (size_t)BN*80*(HF/4)*(WF/4);
    float* rb   = ws + off; off += (size_t)BN*80*(HF/4)*(WF/4);
    float* tmpb = ws + off; off += (size_t)BN*5*(HF/2)*(WF/2);

    gate_conv_kernel<<<32*GCHUNKS, 256, 0, stream>>>(x, wr, br, partial);
    gate_fc_kernel<<<1, 64, 0, stream>>>(partial, wl, bl, g);
    {
        int n = BN*4*HWF;
        init_kernel<<<(n+255)/256, 256, 0, stream>>>(x, flow, mask, wb0, wb1);
    }
    const int SC[9] = {4,4,4,2,2,2,1,1,1};
    for (int i = 0; i < 9; ++i) {
        int s = SC[i];
        int sh = HF/s, sw = WF/s;
        int h = sh/2, w = sw/2;
        int h2 = h/2, w2 = w/2;
        {
            int n = BN*17*sh*sw;
            prepare_kernel<<<(n+255)/256,256,0,stream>>>(x, wb0, wb1, mask, flow, g, i, tin, s, sh, sw);
        }
        {
            int n = BN*40*h*w;
            conv3x3_kernel<<<(n+255)/256,256,0,stream>>>(tin, w0a + (size_t)i*40*17*9, b0a + i*40,
                nullptr, g, i, t0, 17, 40, sh, sw, h, w, 2, 0, 1);
        }
        {
            int n = BN*80*h2*w2;
            conv3x3_kernel<<<(n+255)/256,256,0,stream>>>(t0, w0b + (size_t)i*80*40*9, b0b + i*80,
                nullptr, g, i, t1, 40, 80, h, w, h2, w2, 2, 0, 1);
        }
        const float* cin = t1;
        float* cout = ra;
        for (int j = 0; j < 4; ++j) {
            int n = BN*80*h2*w2;
            const float* res = (j == 3) ? t1 : nullptr;
            conv3x3_kernel<<<(n+255)/256,256,0,stream>>>(cin,
                wcb + ((size_t)i*4 + j)*80*80*9, bcb + ((size_t)i*4 + j)*80,
                res, g, i, cout, 80, 80, h2, w2, h2, w2, 1, 1, 1);
            cin = cout;
            cout = (cout == ra) ? rb : ra;
        }
        {
            int n = BN*5*h*w;
            deconv_kernel<<<(n+255)/256,256,0,stream>>>(cin, wlast + (size_t)i*5*80*16, blast + i*5,
                g, i, tmpb, h2, w2);
        }
        {
            int n = BN*5*HWF;
            upsample_accum_kernel<<<(n+255)/256,256,0,stream>>>(tmpb, g, i, flow, mask, h, w, 2*s, (float)(2*s));
        }
        {
            int n = BN*6*HWF;
            warp_kernel<<<(n+255)/256,256,0,stream>>>(x, flow, g, i, wb0, wb1);
        }
    }
    {
        int n = BN*3*HWF;
        final_kernel<<<(n+255)/256,256,0,stream>>>(wb0, wb1, mask, (float*)d_out);
    }
}